// Round 1
// baseline (106.917 us; speedup 1.0000x reference)
//
#include <hip/hip_runtime.h>

// AdaptiveTokenMixer: out[b,n,:] = sum_{p=0..7} alpha[b,n,p] * x[b,n+p,:]
// alpha = normalized blend of sigmoid(beta)*softmax(w) and temporal-decay
// softmax over valid offsets; zero for invalid rows.

#define NEGV (-1e9f)

constexpr int Bc = 8;
constexpr int Nc = 4096;
constexpr int Dc = 256;
constexpr int Kc = 8;
constexpr int ROWS = 4; // rows (waves) per block

__global__ __launch_bounds__(256) void atm_kernel(
    const float* __restrict__ x,
    const float* __restrict__ dt,
    const void* __restrict__ maskp,
    const float* __restrict__ w,
    const float* __restrict__ beta,
    float* __restrict__ out)
{
    const unsigned char* m8 = (const unsigned char*)maskp;
    const int* m32 = (const int*)maskp;
    // mask[0,1] is always true (lengths >= N/2). If stored as bytes,
    // byte[1] != 0; if stored as int32 (or f32), byte[1] == 0.
    const bool is_byte = (m8[1] != 0);

    const int wave = threadIdx.x >> 6;
    const int lane = threadIdx.x & 63;
    const int tiles_per_b = Nc / ROWS;
    const int b = blockIdx.x / tiles_per_b;
    const int tile = blockIdx.x % tiles_per_b;
    const int n = tile * ROWS + wave;
    const long rowm = (long)b * Nc + n;

    float4* __restrict__ out4 = (float4*)out;
    const float4* __restrict__ x4 = (const float4*)x;
    const long o4 = rowm * (Dc / 4) + lane;

    auto getm = [&](long i) -> bool {
        return is_byte ? (m8[i] != 0) : (m32[i] != 0);
    };

    const bool valid_n = getm(rowm);
    if (!valid_n) {
        out4[o4] = make_float4(0.f, 0.f, 0.f, 0.f);
        return;
    }

    // softmax(w) and sigmoid(beta) — tiny, computed per-thread (L1-hit loads)
    float wv[Kc];
    float wmax = -1e30f;
#pragma unroll
    for (int p = 0; p < Kc; ++p) { wv[p] = w[p]; wmax = fmaxf(wmax, wv[p]); }
    float wsum = 0.f;
#pragma unroll
    for (int p = 0; p < Kc; ++p) { wv[p] = expf(wv[p] - wmax); wsum += wv[p]; }
    const float winv = 1.0f / wsum;
    const float bsig = 1.0f / (1.0f + expf(-beta[0]));

    const float dtn = dt[rowm];
    float lg[Kc];
    bool cv[Kc];
    float mx = -1e30f;
#pragma unroll
    for (int p = 0; p < Kc; ++p) {
        const int np = n + p;
        bool c;
        float t = 0.0f;
        if (p == 0) {
            c = true;
        } else if (np < Nc) {
            c = getm(rowm + p);
            t = fmaxf(dt[rowm + p] - dtn, 0.0f);
        } else {
            c = false;
        }
        const float l = c ? -t : NEGV;
        cv[p] = c;
        lg[p] = l;
        mx = fmaxf(mx, l);
    }

    float th[Kc];
    float tsum = 0.f;
#pragma unroll
    for (int p = 0; p < Kc; ++p) { th[p] = expf(lg[p] - mx); tsum += th[p]; }
    const float tinv = 1.0f / tsum;

    float alpha[Kc];
    float asum = 0.f;
#pragma unroll
    for (int p = 0; p < Kc; ++p) {
        const float a = cv[p] ? (bsig * wv[p] * winv + (1.0f - bsig) * th[p] * tinv)
                              : 0.0f;
        alpha[p] = a;
        asum += a;
    }
    const float norm = 1.0f / fmaxf(asum, 1e-8f);

    float4 acc = make_float4(0.f, 0.f, 0.f, 0.f);
#pragma unroll
    for (int p = 0; p < Kc; ++p) {
        if (n + p < Nc) {
            const float a = alpha[p] * norm;
            const float4 xv = x4[o4 + (long)p * (Dc / 4)];
            acc.x = fmaf(a, xv.x, acc.x);
            acc.y = fmaf(a, xv.y, acc.y);
            acc.z = fmaf(a, xv.z, acc.z);
            acc.w = fmaf(a, xv.w, acc.w);
        }
    }
    out4[o4] = acc;
}

extern "C" void kernel_launch(void* const* d_in, const int* in_sizes, int n_in,
                              void* d_out, int out_size, void* d_ws, size_t ws_size,
                              hipStream_t stream) {
    const float* x    = (const float*)d_in[0];
    const float* dt   = (const float*)d_in[1];
    const void*  mask = d_in[2];
    const float* w    = (const float*)d_in[3];
    const float* beta = (const float*)d_in[4];
    float* out = (float*)d_out;

    dim3 grid(Bc * Nc / ROWS);
    dim3 block(256);
    atm_kernel<<<grid, block, 0, stream>>>(x, dt, mask, w, beta, out);
}

// Round 2
// 93.297 us; speedup vs baseline: 1.1460x; 1.1460x over previous
//
#include <hip/hip_runtime.h>

// AdaptiveTokenMixer: out[b,n,:] = sum_{p=0..7} alpha[b,n,p] * x[b,n+p,:]
// Block-tiled: stage 39 x-rows in LDS once (kills the 8x global re-read),
// compute the 32x8 alpha table with one thread per (row, offset) using
// 8-lane shuffle reductions (kills the 17-expf/26-load per-thread redundancy
// of the previous version), then 4 waves emit 8 rows each from LDS.

#define NEGV (-1e9f)

constexpr int Bc = 8;
constexpr int Nc = 4096;
constexpr int D4 = 64;            // 256 floats = 64 float4 per row
constexpr int Kc = 8;
constexpr int Tr = 32;            // output rows per block
constexpr int XR = Tr + Kc - 1;   // 39 staged x rows

__global__ __launch_bounds__(256) void atm_kernel(
    const float* __restrict__ x,
    const float* __restrict__ dt,
    const void* __restrict__ maskp,
    const float* __restrict__ w,
    const float* __restrict__ beta,
    float* __restrict__ out)
{
    __shared__ float4 xs[XR * D4];      // 39 KB
    __shared__ float alphas[Tr][Kc];    // 1 KB

    const int tid = threadIdx.x;
    const int tiles_per_b = Nc / Tr;    // 128
    const int b = blockIdx.x / tiles_per_b;
    const int n0 = (blockIdx.x % tiles_per_b) * Tr;
    const long row0 = (long)b * Nc + n0;

    // ---- stage x tile (coalesced float4) ----
    const float4* __restrict__ x4 = (const float4*)x;
    const long total4 = (long)Bc * Nc * D4;
    const long base4 = row0 * D4;
#pragma unroll
    for (int i = tid; i < XR * D4; i += 256) {
        const long g = base4 + i;
        xs[i] = (g < total4) ? x4[g] : make_float4(0.f, 0.f, 0.f, 0.f);
    }

    // ---- phase 1: one thread per (row, offset) computes alpha ----
    {
        const int r = tid >> 3;         // 0..31
        const int p = tid & 7;          // 0..7
        const int n = n0 + r;
        const long rowm = row0 + r;

        const unsigned char* m8 = (const unsigned char*)maskp;
        const int* m32 = (const int*)maskp;
        // mask[0,1] is always true (lengths >= N/2): byte layout iff byte 1 != 0
        const bool is_byte = (m8[1] != 0);
        auto getm = [&](long i) -> bool {
            return is_byte ? (m8[i] != 0) : (m32[i] != 0);
        };

        bool c;
        float td = 0.f;
        if (p == 0) {
            c = getm(rowm);
        } else if (n + p < Nc) {
            c = getm(rowm) && getm(rowm + p);
            td = fmaxf(dt[rowm + p] - dt[rowm], 0.f);
        } else {
            c = false;
        }
        const float lg = c ? -td : NEGV;

        // reductions over the 8-lane offset group (lanes r*8..r*8+7)
        float mx = lg;
        mx = fmaxf(mx, __shfl_xor(mx, 1));
        mx = fmaxf(mx, __shfl_xor(mx, 2));
        mx = fmaxf(mx, __shfl_xor(mx, 4));
        const float th = expf(lg - mx);
        float tsum = th;
        tsum += __shfl_xor(tsum, 1);
        tsum += __shfl_xor(tsum, 2);
        tsum += __shfl_xor(tsum, 4);

        const float wv = w[p];
        float wmax = wv;
        wmax = fmaxf(wmax, __shfl_xor(wmax, 1));
        wmax = fmaxf(wmax, __shfl_xor(wmax, 2));
        wmax = fmaxf(wmax, __shfl_xor(wmax, 4));
        const float we = expf(wv - wmax);
        float wsum = we;
        wsum += __shfl_xor(wsum, 1);
        wsum += __shfl_xor(wsum, 2);
        wsum += __shfl_xor(wsum, 4);

        const float bsig = 1.0f / (1.0f + expf(-beta[0]));
        const float a = c ? (bsig * we / wsum + (1.0f - bsig) * th / tsum) : 0.f;
        float asum = a;
        asum += __shfl_xor(asum, 1);
        asum += __shfl_xor(asum, 2);
        asum += __shfl_xor(asum, 4);
        alphas[r][p] = a / fmaxf(asum, 1e-8f);
        // note: invalid row n -> all c false -> all alpha 0 -> output row = 0,
        // matching the reference's final valid_mask multiply.
    }

    __syncthreads();

    // ---- phase 2: each wave emits 8 rows from LDS ----
    const int wave = tid >> 6;          // 0..3
    const int lane = tid & 63;          // float4 column
    float4* __restrict__ out4 = (float4*)out;
#pragma unroll
    for (int rr = 0; rr < 8; ++rr) {
        const int r = wave * 8 + rr;
        float4 acc = make_float4(0.f, 0.f, 0.f, 0.f);
#pragma unroll
        for (int p = 0; p < Kc; ++p) {
            const float a = alphas[r][p];           // LDS broadcast
            const float4 xv = xs[(r + p) * D4 + lane];
            acc.x = fmaf(a, xv.x, acc.x);
            acc.y = fmaf(a, xv.y, acc.y);
            acc.z = fmaf(a, xv.z, acc.z);
            acc.w = fmaf(a, xv.w, acc.w);
        }
        out4[(row0 + r) * D4 + lane] = acc;
    }
}

extern "C" void kernel_launch(void* const* d_in, const int* in_sizes, int n_in,
                              void* d_out, int out_size, void* d_ws, size_t ws_size,
                              hipStream_t stream) {
    const float* x    = (const float*)d_in[0];
    const float* dt   = (const float*)d_in[1];
    const void*  mask = d_in[2];
    const float* w    = (const float*)d_in[3];
    const float* beta = (const float*)d_in[4];
    float* out = (float*)d_out;

    dim3 grid(Bc * Nc / Tr);   // 1024 blocks
    dim3 block(256);
    atm_kernel<<<grid, block, 0, stream>>>(x, dt, mask, w, beta, out);
}

// Round 6
// 91.497 us; speedup vs baseline: 1.1685x; 1.0197x over previous
//
#include <hip/hip_runtime.h>

// AdaptiveTokenMixer: out[b,n,:] = sum_{p=0..7} alpha[b,n,p] * x[b,n+p,:]
//
// Wave-strip design, no LDS, no barriers:
//  - each wave owns 8 consecutive output rows; lane = r*8+p maps 1:1 onto the
//    8x8 (row, offset) alpha table, computed with 8-lane shuffle reductions.
//  - the 15 x-rows the strip needs are loaded upfront into registers
//    (15-deep MLP; overlap rows hit L2/L3 since x (32 MB) fits in L3).
//  - accumulate with __shfl broadcast of alpha from the owning lane.

#define NEGV (-1e9f)

constexpr int Bc = 8;
constexpr int Nc = 4096;
constexpr int D4 = 64;   // 256 floats = 64 float4 per row
constexpr int Rw = 8;    // rows per wave
constexpr int XR = 15;   // x rows needed per strip

__global__ __launch_bounds__(256) void atm_kernel(
    const float* __restrict__ x,
    const float* __restrict__ dt,
    const void* __restrict__ maskp,
    const float* __restrict__ w,
    const float* __restrict__ beta,
    float* __restrict__ out)
{
    const int tid = threadIdx.x;
    const int lane = tid & 63;
    const int gw = blockIdx.x * 4 + (tid >> 6);     // global wave id
    const int waves_per_b = Nc / Rw;                // 512
    const int b = gw / waves_per_b;
    const int n0 = (gw % waves_per_b) * Rw;
    const long row0 = (long)b * Nc + n0;

    // ---- per-lane alpha for (row r_l, offset p_l) ----
    const int r_l = lane >> 3;
    const int p_l = lane & 7;
    const int n = n0 + r_l;
    const long rowm = row0 + r_l;

    const unsigned char* m8 = (const unsigned char*)maskp;
    const int* m32 = (const int*)maskp;
    // mask[0,1] is always true (lengths >= N/2): byte layout iff byte 1 != 0
    const bool is_byte = (m8[1] != 0);
    auto getm = [&](long i) -> bool {
        return is_byte ? (m8[i] != 0) : (m32[i] != 0);
    };

    bool c;
    float td = 0.f;
    if (p_l == 0) {
        c = getm(rowm);
    } else if (n + p_l < Nc) {
        c = getm(rowm) && getm(rowm + p_l);
        td = fmaxf(dt[rowm + p_l] - dt[rowm], 0.f);
    } else {
        c = false;
    }
    const float lg = c ? -td : NEGV;

    // temporal softmax over the 8-lane offset group
    float mx = lg;
    mx = fmaxf(mx, __shfl_xor(mx, 1));
    mx = fmaxf(mx, __shfl_xor(mx, 2));
    mx = fmaxf(mx, __shfl_xor(mx, 4));
    const float th = expf(lg - mx);
    float tsum = th;
    tsum += __shfl_xor(tsum, 1);
    tsum += __shfl_xor(tsum, 2);
    tsum += __shfl_xor(tsum, 4);

    // learnable-offset softmax
    const float wv = w[p_l];
    float wmax = wv;
    wmax = fmaxf(wmax, __shfl_xor(wmax, 1));
    wmax = fmaxf(wmax, __shfl_xor(wmax, 2));
    wmax = fmaxf(wmax, __shfl_xor(wmax, 4));
    const float we = expf(wv - wmax);
    float wsum = we;
    wsum += __shfl_xor(wsum, 1);
    wsum += __shfl_xor(wsum, 2);
    wsum += __shfl_xor(wsum, 4);

    const float bsig = 1.0f / (1.0f + expf(-beta[0]));
    const float a = c ? (bsig * we / wsum + (1.0f - bsig) * th / tsum) : 0.f;
    float asum = a;
    asum += __shfl_xor(asum, 1);
    asum += __shfl_xor(asum, 2);
    asum += __shfl_xor(asum, 4);
    const float aval = a / fmaxf(asum, 1e-8f);
    // invalid row -> all c false -> aval 0 -> output row 0 (matches the
    // reference's final valid_mask multiply).

    // ---- load all 15 x rows upfront (registers, max MLP) ----
    const float4* __restrict__ x4 = (const float4*)x;
    float4 win[XR];
#pragma unroll
    for (int j = 0; j < XR; ++j) {
        win[j] = (n0 + j < Nc) ? x4[(row0 + j) * D4 + lane]
                               : make_float4(0.f, 0.f, 0.f, 0.f);
    }

    // ---- accumulate + store 8 rows ----
    float4* __restrict__ out4 = (float4*)out;
#pragma unroll
    for (int r = 0; r < Rw; ++r) {
        float4 acc = make_float4(0.f, 0.f, 0.f, 0.f);
#pragma unroll
        for (int p = 0; p < 8; ++p) {
            const float av = __shfl(aval, r * 8 + p);
            const float4 xv = win[r + p];
            acc.x = fmaf(av, xv.x, acc.x);
            acc.y = fmaf(av, xv.y, acc.y);
            acc.z = fmaf(av, xv.z, acc.z);
            acc.w = fmaf(av, xv.w, acc.w);
        }
        out4[(row0 + r) * D4 + lane] = acc;
    }
}

extern "C" void kernel_launch(void* const* d_in, const int* in_sizes, int n_in,
                              void* d_out, int out_size, void* d_ws, size_t ws_size,
                              hipStream_t stream) {
    const float* x    = (const float*)d_in[0];
    const float* dt   = (const float*)d_in[1];
    const void*  mask = d_in[2];
    const float* w    = (const float*)d_in[3];
    const float* beta = (const float*)d_in[4];
    float* out = (float*)d_out;

    dim3 grid(Bc * Nc / (Rw * 4));   // 1024 blocks, 4 waves each
    dim3 block(256);
    atm_kernel<<<grid, block, 0, stream>>>(x, dt, mask, w, beta, out);
}